// Round 8
// baseline (220.203 us; speedup 1.0000x reference)
//
#include <hip/hip_runtime.h>
#include <hip/hip_bf16.h>
#include <math.h>

// ---------------------------------------------------------------------------
// GATConv forward.  N=100000, E=1.6M, IN=128, OUT*HEADS=128 (OUT=32, H=4).
// Round 8:
//   - prep_w: one-time W -> bf16 hi/lo split (Wh, Wl) in workspace.
//   - gemm_z: UNFUSED, 512 threads / 8 waves, each wave owns 16 channels.
//     B frags loaded directly as bf16x8 (32 VGPR), acc 16 VGPR, capped at
//     128 VGPR via __launch_bounds__(512,4) -> no spills, 16 waves/CU.
//     x staged once to swizzled LDS (hi/lo), shared by all 8 waves.
//   - deg_cnt: separate lightweight kernel (full occupancy, no LDS tax).
//   - node_scan (node_e || scan1), scan2, fill, gather: unchanged from r7.
// ---------------------------------------------------------------------------

typedef __attribute__((ext_vector_type(8))) short bf16x8;
typedef __attribute__((ext_vector_type(4))) float f32x4;

__device__ __forceinline__ ushort f2bf(float f) {
  __hip_bfloat16 h = __float2bfloat16(f);   // RNE
  return __builtin_bit_cast(ushort, h);
}
__device__ __forceinline__ float bf2f(ushort u) {
  unsigned v = ((unsigned)u) << 16;
  return __builtin_bit_cast(float, v);
}

__global__ __launch_bounds__(256) void prep_w(
    const float* __restrict__ W, ushort* __restrict__ Wh,
    ushort* __restrict__ Wl) {
  int i = blockIdx.x * 256 + threadIdx.x;   // 16384 total
  float w = W[i];
  ushort hb = f2bf(w);
  Wh[i] = hb;
  Wl[i] = f2bf(w - bf2f(hb));
}

__global__ __launch_bounds__(512, 4) void gemm_z(
    const float* __restrict__ x, const ushort* __restrict__ Wh,
    const ushort* __restrict__ Wl, const float* __restrict__ bias,
    ushort* __restrict__ Zh, int N) {
  __shared__ ushort xh[64 * 128];
  __shared__ ushort xl[64 * 128];
  const int t = threadIdx.x;
  const int lane = t & 63;
  const int wv = t >> 6;                 // wave id: owns channels wv*16..+15
  const int row0 = blockIdx.x * 64;
  const int l15 = lane & 15, l4 = lane >> 4;
  const int ch = wv * 16 + l15;          // ref channel = o*4+h

  // ---- B fragments: direct bf16x8 loads from precomputed Wh/Wl ----
  bf16x8 Bh[4], Bl[4];
#pragma unroll
  for (int kf = 0; kf < 4; ++kf) {
    int off = ch * 128 + kf * 32 + l4 * 8;
    Bh[kf] = *(const bf16x8*)&Wh[off];
    Bl[kf] = *(const bf16x8*)&Wl[off];
  }

  // ---- stage x tile (64 rows) -> LDS bf16 hi/lo, 16B-chunk XOR swizzle ----
#pragma unroll
  for (int i = 0; i < 4; ++i) {
    int f4 = i * 512 + t;                // 2048 float4s
    int r = f4 >> 5;
    int k = (f4 & 31) * 4;
    int gr = row0 + r;
    float4 v = make_float4(0.f, 0.f, 0.f, 0.f);
    if (gr < N) v = ((const float4*)x)[(size_t)gr * 32 + (f4 & 31)];
    float vf[4] = {v.x, v.y, v.z, v.w};
    ushort hs[4], ls[4];
#pragma unroll
    for (int j = 0; j < 4; ++j) {
      hs[j] = f2bf(vf[j]);
      ls[j] = f2bf(vf[j] - bf2f(hs[j]));
    }
    int idx = r * 128 + (k ^ ((r & 7) << 3));
    uint2 hv, lv;
    hv.x = hs[0] | ((unsigned)hs[1] << 16);
    hv.y = hs[2] | ((unsigned)hs[3] << 16);
    lv.x = ls[0] | ((unsigned)ls[1] << 16);
    lv.y = ls[2] | ((unsigned)ls[3] << 16);
    *(uint2*)&xh[idx] = hv;
    *(uint2*)&xl[idx] = lv;
  }
  __syncthreads();

  // ---- MFMA: 4 row-tiles x 4 k-frags x 3 products, 1 ch-tile/wave ----
  f32x4 acc[4];
#pragma unroll
  for (int rt = 0; rt < 4; ++rt) acc[rt] = (f32x4){0.f, 0.f, 0.f, 0.f};

#pragma unroll
  for (int kf = 0; kf < 4; ++kf) {
#pragma unroll
    for (int rt = 0; rt < 4; ++rt) {
      int r = rt * 16 + l15;
      int idx = r * 128 + ((kf * 32 + l4 * 8) ^ ((r & 7) << 3));
      bf16x8 ah = *(const bf16x8*)&xh[idx];
      bf16x8 al = *(const bf16x8*)&xl[idx];
      acc[rt] = __builtin_amdgcn_mfma_f32_16x16x32_bf16(ah, Bh[kf], acc[rt], 0, 0, 0);
      acc[rt] = __builtin_amdgcn_mfma_f32_16x16x32_bf16(al, Bh[kf], acc[rt], 0, 0, 0);
      acc[rt] = __builtin_amdgcn_mfma_f32_16x16x32_bf16(ah, Bl[kf], acc[rt], 0, 0, 0);
    }
  }

  // ---- store Zh head-major; D layout: col=lane&15, row=(lane>>4)*4+j ----
  float bv = bias[ch];
  unsigned zc = (unsigned)((ch & 3) * 32 + (ch >> 2));   // head-major slot
#pragma unroll
  for (int rt = 0; rt < 4; ++rt) {
#pragma unroll
    for (int j = 0; j < 4; ++j) {
      int r = row0 + rt * 16 + l4 * 4 + j;
      if (r < N) Zh[(unsigned)r * 128 + zc] = f2bf(acc[rt][j] + bv);
    }
  }
}

__global__ __launch_bounds__(256) void deg_cnt(
    const int* __restrict__ row, int* __restrict__ deg,
    int* __restrict__ rank, int E) {
  int e = blockIdx.x * 256 + threadIdx.x;
  if (e < E) rank[e] = atomicAdd(&deg[row[e]], 1);
}

// ---- fused: node_e blocks [0, G1) | scan1 blocks [G1, G1+NB) ----
__global__ __launch_bounds__(256) void node_scan(
    const ushort* __restrict__ Zh, const float* __restrict__ a_l,
    const float* __restrict__ a_r, float* __restrict__ el,
    float* __restrict__ er, int N4,
    const int* __restrict__ deg, int* __restrict__ basev,
    int* __restrict__ bsum, int N, int G1) {
  __shared__ float sal[128], sar[128];
  __shared__ int ss[256];
  int t = threadIdx.x;

  if ((int)blockIdx.x < G1) {
    // ---- node_e: el/er[n,h] = sum_o Zh[n,h,o] * a[o*4+h] ----
    if (t < 128) { sal[t] = a_l[t]; sar[t] = a_r[t]; }
    __syncthreads();
    int idx = blockIdx.x * 256 + t;       // n*4 + h
    if (idx >= N4) return;
    int n = idx >> 2, h = idx & 3;
    const ushort* zp = Zh + (unsigned)n * 128 + h * 32;
    float sl = 0.f, sr = 0.f;
#pragma unroll
    for (int q = 0; q < 8; ++q) {
      uint2 zz = *(const uint2*)&zp[q * 4];
      float z0 = bf2f((ushort)(zz.x & 0xffff));
      float z1 = bf2f((ushort)(zz.x >> 16));
      float z2 = bf2f((ushort)(zz.y & 0xffff));
      float z3 = bf2f((ushort)(zz.y >> 16));
      int o = q * 4;
      sl += z0 * sal[(o + 0) * 4 + h] + z1 * sal[(o + 1) * 4 + h]
          + z2 * sal[(o + 2) * 4 + h] + z3 * sal[(o + 3) * 4 + h];
      sr += z0 * sar[(o + 0) * 4 + h] + z1 * sar[(o + 1) * 4 + h]
          + z2 * sar[(o + 2) * 4 + h] + z3 * sar[(o + 3) * 4 + h];
    }
    el[idx] = sl;
    er[idx] = sr;
  } else {
    // ---- scan1: per-256-block exclusive prefix of deg ----
    int bid = (int)blockIdx.x - G1;
    int i = bid * 256 + t;
    int v = (i < N) ? deg[i] : 0;
    ss[t] = v;
    __syncthreads();
#pragma unroll
    for (int off = 1; off < 256; off <<= 1) {
      int u = (t >= off) ? ss[t - off] : 0;
      __syncthreads();
      ss[t] += u;
      __syncthreads();
    }
    if (i < N) basev[i] = ss[t] - v;
    if (t == 255) bsum[bid] = ss[255];
  }
}

__global__ __launch_bounds__(512) void scan2(int* __restrict__ bsum, int NB) {
  __shared__ int s[512];
  int v = (threadIdx.x < NB) ? bsum[threadIdx.x] : 0;
  s[threadIdx.x] = v;
  __syncthreads();
#pragma unroll
  for (int off = 1; off < 512; off <<= 1) {
    int t = (threadIdx.x >= off) ? s[threadIdx.x - off] : 0;
    __syncthreads();
    s[threadIdx.x] += t;
    __syncthreads();
  }
  if (threadIdx.x < NB) bsum[threadIdx.x] = s[threadIdx.x] - v;
}

__global__ __launch_bounds__(256) void fill(
    const int* __restrict__ row, const int* __restrict__ col,
    const int* __restrict__ rank, const int* __restrict__ base,
    const int* __restrict__ bsum, int* __restrict__ sorted_col, int E) {
  int e = blockIdx.x * 256 + threadIdx.x;
  if (e < E) {
    int r = row[e];
    sorted_col[base[r] + bsum[r >> 8] + rank[e]] = col[e];
  }
}

__global__ __launch_bounds__(256) void gather(
    const int* __restrict__ base, const int* __restrict__ bsum,
    const int* __restrict__ deg, const int* __restrict__ sorted_col,
    const float* __restrict__ el, const float* __restrict__ er,
    const ushort* __restrict__ Zh, float* __restrict__ out, int N) {
  int t = threadIdx.x;
  int lane = t & 63;
  int n = blockIdx.x * 4 + (t >> 6);
  if (n >= N) return;
  int h = lane >> 4;                  // head
  int j = lane & 15;                  // edge sub-index within 16-chunk
  int s = base[n] + bsum[n >> 8];
  int d = deg[n];
  int end = s + d;
  float elv = el[((unsigned)n << 2) + h];
  float acc0 = 0.f, acc1 = 0.f, sumA = 0.f;
  const unsigned* Zh32 = (const unsigned*)Zh;
  const unsigned zlane = (unsigned)lane;
  const int bpb = (lane & 48) << 2;   // bpermute byte base = (h*16)*4

  for (int p = s; p < end; p += 16) {
    int cnt = end - p;                // lanes with j < cnt are valid
    // phase A: one exp per (edge, head); invalid lanes carry xv=0, cl6=0
    int cl6 = 0;
    float xv = 0.f;
    if (j < cnt) {
      int cl = sorted_col[p + j];
      float e = elv + er[((unsigned)cl << 2) + h];
      e = fmaxf(e, 0.2f * e);          // LeakyReLU(0.2)
      xv = __expf(e);
      cl6 = cl << 6;                   // dword offset of Zh row
    }
    sumA += xv;
    // phase B: batched broadcasts, batched loads, batched fma (branch-free)
    float xvb[16];
    unsigned addr[16];
#pragma unroll
    for (int jj = 0; jj < 16; ++jj) {
      int a = bpb + (jj << 2);
      xvb[jj] = __builtin_bit_cast(float,
          __builtin_amdgcn_ds_bpermute(a, __builtin_bit_cast(int, xv)));
      addr[jj] = (unsigned)__builtin_amdgcn_ds_bpermute(a, cl6) + zlane;
    }
    unsigned zz[16];
#pragma unroll
    for (int jj = 0; jj < 16; ++jj) zz[jj] = Zh32[addr[jj]];
#pragma unroll
    for (int jj = 0; jj < 16; ++jj) {
      acc0 = fmaf(xvb[jj], __builtin_bit_cast(float, zz[jj] << 16), acc0);
      acc1 = fmaf(xvb[jj], __builtin_bit_cast(float, zz[jj] & 0xffff0000u), acc1);
    }
  }
  // reduce denom over the 16 lanes of this head group
  float sum = sumA;
  sum += __shfl_xor(sum, 1, 64);
  sum += __shfl_xor(sum, 2, 64);
  sum += __shfl_xor(sum, 4, 64);
  sum += __shfl_xor(sum, 8, 64);
  float inv = (d > 0) ? 1.0f / sum : 0.f;
  unsigned o0 = (unsigned)(j << 1);
  unsigned ob = ((unsigned)n << 7) + (o0 << 2) + (unsigned)h;  // o*4+h layout
  out[ob] = acc0 * inv;
  out[ob + 4] = acc1 * inv;
}

extern "C" void kernel_launch(void* const* d_in, const int* in_sizes, int n_in,
                              void* d_out, int out_size, void* d_ws, size_t ws_size,
                              hipStream_t stream) {
  const float* x   = (const float*)d_in[0];
  const int*   row = (const int*)d_in[1];
  const int*   col = (const int*)d_in[2];
  const float* W   = (const float*)d_in[3];
  const float* b   = (const float*)d_in[4];
  const float* a_l = (const float*)d_in[5];
  const float* a_r = (const float*)d_in[6];
  float* out = (float*)d_out;

  const int N = in_sizes[0] / 128;
  const int E = in_sizes[1];
  const int NB = (N + 255) / 256;

  char* w = (char*)d_ws;
  ushort* Zh       = (ushort*)w;             w += (size_t)N * 128 * 2;
  int*   sorted_col= (int*)w;                w += (size_t)E * 4;
  int*   rank      = (int*)w;                w += (size_t)E * 4;
  float* el        = (float*)w;              w += (size_t)N * 4 * 4;
  float* er        = (float*)w;              w += (size_t)N * 4 * 4;
  int*   deg       = (int*)w;                w += (size_t)N * 4;
  int*   base      = (int*)w;                w += (size_t)N * 4;
  int*   bsum      = (int*)w;                w += 512 * 4;
  ushort* Wh       = (ushort*)w;             w += 16384 * 2;
  ushort* Wl       = (ushort*)w;             w += 16384 * 2;

  hipMemsetAsync(deg, 0, (size_t)N * sizeof(int), stream);

  prep_w<<<64, 256, 0, stream>>>(W, Wh, Wl);
  deg_cnt<<<(E + 255) / 256, 256, 0, stream>>>(row, deg, rank, E);
  gemm_z<<<(N + 63) / 64, 512, 0, stream>>>(x, Wh, Wl, b, Zh, N);

  const int G1n = (N * 4 + 255) / 256;       // node_e blocks
  node_scan<<<G1n + NB, 256, 0, stream>>>(Zh, a_l, a_r, el, er, N * 4,
                                          deg, base, bsum, N, G1n);
  scan2<<<1, 512, 0, stream>>>(bsum, NB);
  fill<<<(E + 255) / 256, 256, 0, stream>>>(row, col, rank, base, bsum,
                                            sorted_col, E);
  gather<<<(N + 3) / 4, 256, 0, stream>>>(base, bsum, deg, sorted_col, el, er,
                                          Zh, out, N);
}

// Round 9
// 211.227 us; speedup vs baseline: 1.0425x; 1.0425x over previous
//
#include <hip/hip_runtime.h>
#include <hip/hip_bf16.h>
#include <math.h>

// ---------------------------------------------------------------------------
// GATConv forward.  N=100000, E=1.6M, IN=128, OUT*HEADS=128 (OUT=32, H=4).
// Round 9:
//   - Zh row layout: dword d (= o'*4+h) holds channels (o'*4+h, (o'+16)*4+h)
//     as (lo16, hi16).  ushort slot s(c) = (o&15)*8 + h*2 + (o>>4).
//   - gemm_z: MFMA bf16x3; acc -> LDS transpose (pad 132, ~2-way conflicts)
//     -> fully coalesced 16B/thread global Zh stores (was 16x 2B scatter).
//   - gather: lane=d mapping makes BOTH out stores fully coalesced
//     (out[n*128+lane], out[n*128+64+lane]) and er loads quad-contiguous.
//     Nontemporal out stores keep Zh resident in L2.
//   - deg_cnt / node_scan (node_e || scan1) / scan2 / fill as before,
//     node_e updated for the new Zh layout.
// ---------------------------------------------------------------------------

typedef __attribute__((ext_vector_type(8))) short bf16x8;
typedef __attribute__((ext_vector_type(4))) float f32x4;

__device__ __forceinline__ ushort f2bf(float f) {
  __hip_bfloat16 h = __float2bfloat16(f);   // RNE
  return __builtin_bit_cast(ushort, h);
}
__device__ __forceinline__ float bf2f(ushort u) {
  unsigned v = ((unsigned)u) << 16;
  return __builtin_bit_cast(float, v);
}

__global__ __launch_bounds__(256) void prep_w(
    const float* __restrict__ W, ushort* __restrict__ Wh,
    ushort* __restrict__ Wl) {
  int i = blockIdx.x * 256 + threadIdx.x;   // 16384 total
  float w = W[i];
  ushort hb = f2bf(w);
  Wh[i] = hb;
  Wl[i] = f2bf(w - bf2f(hb));
}

__global__ __launch_bounds__(512, 4) void gemm_z(
    const float* __restrict__ x, const ushort* __restrict__ Wh,
    const ushort* __restrict__ Wl, const float* __restrict__ bias,
    ushort* __restrict__ Zh, int N) {
  __shared__ __align__(16) ushort smem[16384];   // xh | xl ; reused as zs
  ushort* xh = smem;                 // [64*128]
  ushort* xl = smem + 8192;          // [64*128]
  ushort* zs = smem;                 // [64*132] transpose staging (reuse)
  const int t = threadIdx.x;
  const int lane = t & 63;
  const int wv = t >> 6;                 // wave id: owns channels wv*16..+15
  const int row0 = blockIdx.x * 64;
  const int l15 = lane & 15, l4 = lane >> 4;
  const int ch = wv * 16 + l15;          // ref channel = o*4+h

  // ---- B fragments: direct bf16x8 loads from precomputed Wh/Wl ----
  bf16x8 Bh[4], Bl[4];
#pragma unroll
  for (int kf = 0; kf < 4; ++kf) {
    int off = ch * 128 + kf * 32 + l4 * 8;
    Bh[kf] = *(const bf16x8*)&Wh[off];
    Bl[kf] = *(const bf16x8*)&Wl[off];
  }

  // ---- stage x tile (64 rows) -> LDS bf16 hi/lo, 16B-chunk XOR swizzle ----
#pragma unroll
  for (int i = 0; i < 4; ++i) {
    int f4 = i * 512 + t;                // 2048 float4s
    int r = f4 >> 5;
    int k = (f4 & 31) * 4;
    int gr = row0 + r;
    float4 v = make_float4(0.f, 0.f, 0.f, 0.f);
    if (gr < N) v = ((const float4*)x)[(size_t)gr * 32 + (f4 & 31)];
    float vf[4] = {v.x, v.y, v.z, v.w};
    ushort hs[4], ls[4];
#pragma unroll
    for (int j = 0; j < 4; ++j) {
      hs[j] = f2bf(vf[j]);
      ls[j] = f2bf(vf[j] - bf2f(hs[j]));
    }
    int idx = r * 128 + (k ^ ((r & 7) << 3));
    uint2 hv, lv;
    hv.x = hs[0] | ((unsigned)hs[1] << 16);
    hv.y = hs[2] | ((unsigned)hs[3] << 16);
    lv.x = ls[0] | ((unsigned)ls[1] << 16);
    lv.y = ls[2] | ((unsigned)ls[3] << 16);
    *(uint2*)&xh[idx] = hv;
    *(uint2*)&xl[idx] = lv;
  }
  __syncthreads();

  // ---- MFMA: 4 row-tiles x 4 k-frags x 3 products, 1 ch-tile/wave ----
  f32x4 acc[4];
#pragma unroll
  for (int rt = 0; rt < 4; ++rt) acc[rt] = (f32x4){0.f, 0.f, 0.f, 0.f};

#pragma unroll
  for (int kf = 0; kf < 4; ++kf) {
#pragma unroll
    for (int rt = 0; rt < 4; ++rt) {
      int r = rt * 16 + l15;
      int idx = r * 128 + ((kf * 32 + l4 * 8) ^ ((r & 7) << 3));
      bf16x8 ah = *(const bf16x8*)&xh[idx];
      bf16x8 al = *(const bf16x8*)&xl[idx];
      acc[rt] = __builtin_amdgcn_mfma_f32_16x16x32_bf16(ah, Bh[kf], acc[rt], 0, 0, 0);
      acc[rt] = __builtin_amdgcn_mfma_f32_16x16x32_bf16(al, Bh[kf], acc[rt], 0, 0, 0);
      acc[rt] = __builtin_amdgcn_mfma_f32_16x16x32_bf16(ah, Bl[kf], acc[rt], 0, 0, 0);
    }
  }
  __syncthreads();   // xh/xl dead; reuse as zs

  // ---- acc -> LDS (packed slot layout), then coalesced global stores ----
  // slot s(ch): o=ch>>2, h=ch&3, o'=o&15 -> s = o'*8 + h*2 + (o>>4)
  {
    float bv = bias[ch];
    int o = ch >> 2, h = ch & 3;
    int s = (o & 15) * 8 + h * 2 + (o >> 4);
#pragma unroll
    for (int rt = 0; rt < 4; ++rt) {
#pragma unroll
      for (int j = 0; j < 4; ++j) {
        int r = rt * 16 + l4 * 4 + j;
        zs[r * 132 + s] = f2bf(acc[rt][j] + bv);
      }
    }
  }
  __syncthreads();
  {
    int r = t >> 3;                 // 64 rows, 8 threads/row
    int c = t & 7;                  // 16-ushort chunk
    int gr = row0 + r;
    if (gr < N) {
      uint4 v0 = *(const uint4*)&zs[r * 132 + c * 16];
      uint4 v1 = *(const uint4*)&zs[r * 132 + c * 16 + 8];
      *(uint4*)&Zh[(size_t)gr * 128 + c * 16] = v0;
      *(uint4*)&Zh[(size_t)gr * 128 + c * 16 + 8] = v1;
    }
  }
}

__global__ __launch_bounds__(256) void deg_cnt(
    const int* __restrict__ row, int* __restrict__ deg,
    int* __restrict__ rank, int E) {
  int e = blockIdx.x * 256 + threadIdx.x;
  if (e < E) rank[e] = atomicAdd(&deg[row[e]], 1);
}

// ---- fused: node_e blocks [0, G1) | scan1 blocks [G1, G1+NB) ----
__global__ __launch_bounds__(256) void node_scan(
    const ushort* __restrict__ Zh, const float* __restrict__ a_l,
    const float* __restrict__ a_r, float* __restrict__ el,
    float* __restrict__ er, int N4,
    const int* __restrict__ deg, int* __restrict__ basev,
    int* __restrict__ bsum, int N, int G1) {
  __shared__ float sal[128], sar[128];
  __shared__ int ss[256];
  int t = threadIdx.x;

  if ((int)blockIdx.x < G1) {
    // ---- node_e: el/er[n,h] = sum_o Z[n,o,h]*a[o*4+h]  (new Zh layout) ----
    if (t < 128) { sal[t] = a_l[t]; sar[t] = a_r[t]; }
    __syncthreads();
    int idx = blockIdx.x * 256 + t;       // n*4 + h
    if (idx >= N4) return;
    int n = idx >> 2, h = idx & 3;
    const unsigned* zp = (const unsigned*)Zh + (unsigned)n * 64 + h;
    float sl = 0.f, sr = 0.f;
#pragma unroll
    for (int o = 0; o < 16; ++o) {
      unsigned zz = zp[o * 4];            // dword d = o*4+h
      float zlo = bf2f((ushort)(zz & 0xffff));       // channel o*4+h
      float zhi = bf2f((ushort)(zz >> 16));          // channel (o+16)*4+h
      int c = (o << 2) + h;
      sl += zlo * sal[c] + zhi * sal[c + 64];
      sr += zlo * sar[c] + zhi * sar[c + 64];
    }
    el[idx] = sl;
    er[idx] = sr;
  } else {
    // ---- scan1: per-256-block exclusive prefix of deg ----
    int bid = (int)blockIdx.x - G1;
    int i = bid * 256 + t;
    int v = (i < N) ? deg[i] : 0;
    ss[t] = v;
    __syncthreads();
#pragma unroll
    for (int off = 1; off < 256; off <<= 1) {
      int u = (t >= off) ? ss[t - off] : 0;
      __syncthreads();
      ss[t] += u;
      __syncthreads();
    }
    if (i < N) basev[i] = ss[t] - v;
    if (t == 255) bsum[bid] = ss[255];
  }
}

__global__ __launch_bounds__(512) void scan2(int* __restrict__ bsum, int NB) {
  __shared__ int s[512];
  int v = (threadIdx.x < NB) ? bsum[threadIdx.x] : 0;
  s[threadIdx.x] = v;
  __syncthreads();
#pragma unroll
  for (int off = 1; off < 512; off <<= 1) {
    int t = (threadIdx.x >= off) ? s[threadIdx.x - off] : 0;
    __syncthreads();
    s[threadIdx.x] += t;
    __syncthreads();
  }
  if (threadIdx.x < NB) bsum[threadIdx.x] = s[threadIdx.x] - v;
}

__global__ __launch_bounds__(256) void fill(
    const int* __restrict__ row, const int* __restrict__ col,
    const int* __restrict__ rank, const int* __restrict__ base,
    const int* __restrict__ bsum, int* __restrict__ sorted_col, int E) {
  int e = blockIdx.x * 256 + threadIdx.x;
  if (e < E) {
    int r = row[e];
    sorted_col[base[r] + bsum[r >> 8] + rank[e]] = col[e];
  }
}

__global__ __launch_bounds__(256) void gather(
    const int* __restrict__ base, const int* __restrict__ bsum,
    const int* __restrict__ deg, const int* __restrict__ sorted_col,
    const float* __restrict__ el, const float* __restrict__ er,
    const ushort* __restrict__ Zh, float* __restrict__ out, int N) {
  int t = threadIdx.x;
  int lane = t & 63;
  int n = blockIdx.x * 4 + (t >> 6);
  if (n >= N) return;
  int h = lane & 3;                   // head
  int jj = lane >> 2;                 // edge sub-index within 16-chunk
  int s = base[n] + bsum[n >> 8];
  int d = deg[n];
  int end = s + d;
  float elv = el[((unsigned)n << 2) + h];
  float acc0 = 0.f, acc1 = 0.f, sumA = 0.f;
  const unsigned* Zh32 = (const unsigned*)Zh;
  const unsigned zlane = (unsigned)lane;
  const int bpb = (lane & 3) << 2;    // bpermute byte base: source = jj*4+h

  for (int p = s; p < end; p += 16) {
    int cnt = end - p;                // slots with jj < cnt are valid
    // phase A: one exp per (edge, head); quad-contiguous er loads
    int cl6 = 0;
    float xv = 0.f;
    if (jj < cnt) {
      int cl = sorted_col[p + jj];
      float e = elv + er[((unsigned)cl << 2) + h];
      e = fmaxf(e, 0.2f * e);          // LeakyReLU(0.2)
      xv = __expf(e);
      cl6 = cl << 6;                   // dword offset of Zh row
    }
    sumA += xv;
    // phase B: batched broadcasts, batched loads, batched fma (branch-free)
    float xvb[16];
    unsigned addr[16];
#pragma unroll
    for (int q = 0; q < 16; ++q) {
      int a = bpb + (q << 4);          // lane q*4+h
      xvb[q] = __builtin_bit_cast(float,
          __builtin_amdgcn_ds_bpermute(a, __builtin_bit_cast(int, xv)));
      addr[q] = (unsigned)__builtin_amdgcn_ds_bpermute(a, cl6) + zlane;
    }
    unsigned zz[16];
#pragma unroll
    for (int q = 0; q < 16; ++q) zz[q] = Zh32[addr[q]];
#pragma unroll
    for (int q = 0; q < 16; ++q) {
      acc0 = fmaf(xvb[q], __builtin_bit_cast(float, zz[q] << 16), acc0);
      acc1 = fmaf(xvb[q], __builtin_bit_cast(float, zz[q] & 0xffff0000u), acc1);
    }
  }
  // reduce denom over the 16 lanes of this head (bits 2..5)
  float sum = sumA;
  sum += __shfl_xor(sum, 4, 64);
  sum += __shfl_xor(sum, 8, 64);
  sum += __shfl_xor(sum, 16, 64);
  sum += __shfl_xor(sum, 32, 64);
  float inv = (d > 0) ? 1.0f / sum : 0.f;
  // lane = o'*4+h exactly -> coalesced stores
  unsigned ob = ((unsigned)n << 7) + zlane;
  __builtin_nontemporal_store(acc0 * inv, &out[ob]);
  __builtin_nontemporal_store(acc1 * inv, &out[ob + 64]);
}

extern "C" void kernel_launch(void* const* d_in, const int* in_sizes, int n_in,
                              void* d_out, int out_size, void* d_ws, size_t ws_size,
                              hipStream_t stream) {
  const float* x   = (const float*)d_in[0];
  const int*   row = (const int*)d_in[1];
  const int*   col = (const int*)d_in[2];
  const float* W   = (const float*)d_in[3];
  const float* b   = (const float*)d_in[4];
  const float* a_l = (const float*)d_in[5];
  const float* a_r = (const float*)d_in[6];
  float* out = (float*)d_out;

  const int N = in_sizes[0] / 128;
  const int E = in_sizes[1];
  const int NB = (N + 255) / 256;

  char* w = (char*)d_ws;
  ushort* Zh       = (ushort*)w;             w += (size_t)N * 128 * 2;
  int*   sorted_col= (int*)w;                w += (size_t)E * 4;
  int*   rank      = (int*)w;                w += (size_t)E * 4;
  float* el        = (float*)w;              w += (size_t)N * 4 * 4;
  float* er        = (float*)w;              w += (size_t)N * 4 * 4;
  int*   deg       = (int*)w;                w += (size_t)N * 4;
  int*   base      = (int*)w;                w += (size_t)N * 4;
  int*   bsum      = (int*)w;                w += 512 * 4;
  ushort* Wh       = (ushort*)w;             w += 16384 * 2;
  ushort* Wl       = (ushort*)w;             w += 16384 * 2;

  hipMemsetAsync(deg, 0, (size_t)N * sizeof(int), stream);

  prep_w<<<64, 256, 0, stream>>>(W, Wh, Wl);
  deg_cnt<<<(E + 255) / 256, 256, 0, stream>>>(row, deg, rank, E);
  gemm_z<<<(N + 63) / 64, 512, 0, stream>>>(x, Wh, Wl, b, Zh, N);

  const int G1n = (N * 4 + 255) / 256;       // node_e blocks
  node_scan<<<G1n + NB, 256, 0, stream>>>(Zh, a_l, a_r, el, er, N * 4,
                                          deg, base, bsum, N, G1n);
  scan2<<<1, 512, 0, stream>>>(bsum, NB);
  fill<<<(E + 255) / 256, 256, 0, stream>>>(row, col, rank, base, bsum,
                                            sorted_col, E);
  gather<<<(N + 3) / 4, 256, 0, stream>>>(base, bsum, deg, sorted_col, el, er,
                                          Zh, out, N);
}

// Round 10
// 195.240 us; speedup vs baseline: 1.1279x; 1.0819x over previous
//
#include <hip/hip_runtime.h>
#include <hip/hip_bf16.h>
#include <math.h>

// ---------------------------------------------------------------------------
// GATConv forward.  N=100000, E=1.6M, IN=128, OUT*HEADS=128 (OUT=32, H=4).
// Round 10:
//   - prep0: one kernel = {W -> bf16 hi/lo split} + {deg := 0}.
//   - gemm_deg: grid-fused.  Head blocks: 128-row MFMA bf16x2 gemm
//     (x bf16-hi only; W split hi/lo -> 2 products), LDS-transpose epilogue
//     with packed-slot Zh layout + FUSED el/er from the zs tile.
//     Tail blocks: deg_cnt with rank capture (lean config -> no occupancy tax).
//   - scan1 -> scan2 -> fill -> gather (round-9 gather, unchanged).
//   Zh row layout: dword d (= o'*4+h) holds channels (o'*4+h, (o'+16)*4+h);
//   ushort slot s(ch) = (o&15)*8 + h*2 + (o>>4).
// ---------------------------------------------------------------------------

typedef __attribute__((ext_vector_type(8))) short bf16x8;
typedef __attribute__((ext_vector_type(4))) float f32x4;

__device__ __forceinline__ ushort f2bf(float f) {
  __hip_bfloat16 h = __float2bfloat16(f);   // RNE
  return __builtin_bit_cast(ushort, h);
}
__device__ __forceinline__ float bf2f(ushort u) {
  unsigned v = ((unsigned)u) << 16;
  return __builtin_bit_cast(float, v);
}

// ---- W -> bf16 hi/lo split  +  deg zeroing, one dispatch ----
__global__ __launch_bounds__(512) void prep0(
    const float* __restrict__ W, ushort* __restrict__ Wh,
    ushort* __restrict__ Wl, int* __restrict__ deg, int N) {
  int i = blockIdx.x * 512 + threadIdx.x;
  if (i < 16384) {
    float w = W[i];
    ushort hb = f2bf(w);
    Wh[i] = hb;
    Wl[i] = f2bf(w - bf2f(hb));
  }
  if (i < N) deg[i] = 0;
}

// ---- fused: gemm blocks [0, G1) | deg_cnt blocks [G1, G1+G2) ----
__global__ __launch_bounds__(512, 4) void gemm_deg(
    const float* __restrict__ x, const ushort* __restrict__ Wh,
    const ushort* __restrict__ Wl, const float* __restrict__ bias,
    const float* __restrict__ a_l, const float* __restrict__ a_r,
    ushort* __restrict__ Zh, float* __restrict__ el, float* __restrict__ er,
    int N, const int* __restrict__ row, int* __restrict__ deg,
    int* __restrict__ rank, int E, int G1) {
  __shared__ __align__(16) ushort smem[16896];   // xh[128*128] ; reused zs[128*132]
  __shared__ float sal[128], sar[128];

  if ((int)blockIdx.x >= G1) {
    int e = ((int)blockIdx.x - G1) * 512 + threadIdx.x;
    if (e < E) rank[e] = atomicAdd(&deg[row[e]], 1);
    return;
  }

  const int t = threadIdx.x;
  const int lane = t & 63;
  const int wv = t >> 6;                 // wave id: owns channels wv*16..+15
  const int row0 = blockIdx.x * 128;
  const int l15 = lane & 15, l4 = lane >> 4;
  const int ch = wv * 16 + l15;          // ref channel = o*4+h

  if (t < 128) { sal[t] = a_l[t]; sar[t] = a_r[t]; }

  // ---- B fragments: direct bf16x8 loads from precomputed Wh/Wl ----
  bf16x8 Bh[4], Bl[4];
#pragma unroll
  for (int kf = 0; kf < 4; ++kf) {
    int off = ch * 128 + kf * 32 + l4 * 8;
    Bh[kf] = *(const bf16x8*)&Wh[off];
    Bl[kf] = *(const bf16x8*)&Wl[off];
  }

  // ---- stage x tile (128 rows) -> LDS bf16 hi, 16B-chunk XOR swizzle ----
  ushort* xh = smem;
#pragma unroll
  for (int i = 0; i < 8; ++i) {
    int f4 = i * 512 + t;                // 4096 float4s
    int r = f4 >> 5;
    int k = (f4 & 31) * 4;
    int gr = row0 + r;
    float4 v = make_float4(0.f, 0.f, 0.f, 0.f);
    if (gr < N) v = ((const float4*)x)[(size_t)gr * 32 + (f4 & 31)];
    int idx = r * 128 + (k ^ ((r & 7) << 3));
    uint2 hv;
    hv.x = f2bf(v.x) | ((unsigned)f2bf(v.y) << 16);
    hv.y = f2bf(v.z) | ((unsigned)f2bf(v.w) << 16);
    *(uint2*)&xh[idx] = hv;
  }
  __syncthreads();

  // ---- MFMA: 8 row-tiles x 4 k-frags x 2 products, 1 ch-tile/wave ----
  f32x4 acc[8];
#pragma unroll
  for (int rt = 0; rt < 8; ++rt) acc[rt] = (f32x4){0.f, 0.f, 0.f, 0.f};

#pragma unroll
  for (int kf = 0; kf < 4; ++kf) {
#pragma unroll
    for (int rt = 0; rt < 8; ++rt) {
      int r = rt * 16 + l15;
      int idx = r * 128 + ((kf * 32 + l4 * 8) ^ ((r & 7) << 3));
      bf16x8 ah = *(const bf16x8*)&xh[idx];
      acc[rt] = __builtin_amdgcn_mfma_f32_16x16x32_bf16(ah, Bh[kf], acc[rt], 0, 0, 0);
      acc[rt] = __builtin_amdgcn_mfma_f32_16x16x32_bf16(ah, Bl[kf], acc[rt], 0, 0, 0);
    }
  }
  __syncthreads();   // xh dead; reuse as zs

  // ---- acc -> LDS packed-slot tile ----
  // slot s(ch): o=ch>>2, h=ch&3, o'=o&15 -> s = o'*8 + h*2 + (o>>4)
  ushort* zs = smem;   // [128][132]
  {
    float bv = bias[ch];
    int o = ch >> 2, h = ch & 3;
    int s = (o & 15) * 8 + h * 2 + (o >> 4);
#pragma unroll
    for (int rt = 0; rt < 8; ++rt) {
#pragma unroll
      for (int j = 0; j < 4; ++j) {
        int r = rt * 16 + l4 * 4 + j;
        zs[r * 132 + s] = f2bf(acc[rt][j] + bv);
      }
    }
  }
  __syncthreads();

  // ---- coalesced Zh stores + fused el/er (4 threads/row, 1 head each) ----
  {
    int r = t >> 2;                 // 0..127
    int h = t & 3;                  // head AND store chunk
    int gr = row0 + r;
    if (gr < N) {
#pragma unroll
      for (int q = 0; q < 4; ++q) {
        uint4 v = *(const uint4*)&zs[r * 132 + h * 32 + q * 8];
        *(uint4*)&Zh[(size_t)gr * 128 + h * 32 + q * 8] = v;
      }
      float sl = 0.f, sr = 0.f;
#pragma unroll
      for (int op = 0; op < 16; ++op) {
        unsigned zz = *(const unsigned*)&zs[r * 132 + op * 8 + h * 2];
        float zlo = bf2f((ushort)(zz & 0xffff));     // channel op*4+h
        float zhi = bf2f((ushort)(zz >> 16));        // channel (op+16)*4+h
        int c = (op << 2) + h;
        sl += zlo * sal[c] + zhi * sal[c + 64];
        sr += zlo * sar[c] + zhi * sar[c + 64];
      }
      el[(unsigned)gr * 4 + h] = sl;
      er[(unsigned)gr * 4 + h] = sr;
    }
  }
}

__global__ __launch_bounds__(256) void scan1(
    const int* __restrict__ deg, int* __restrict__ base,
    int* __restrict__ bsum, int N) {
  __shared__ int s[256];
  int i = blockIdx.x * 256 + threadIdx.x;
  int v = (i < N) ? deg[i] : 0;
  s[threadIdx.x] = v;
  __syncthreads();
#pragma unroll
  for (int off = 1; off < 256; off <<= 1) {
    int t = (threadIdx.x >= off) ? s[threadIdx.x - off] : 0;
    __syncthreads();
    s[threadIdx.x] += t;
    __syncthreads();
  }
  if (i < N) base[i] = s[threadIdx.x] - v;
  if (threadIdx.x == 255) bsum[blockIdx.x] = s[255];
}

__global__ __launch_bounds__(512) void scan2(int* __restrict__ bsum, int NB) {
  __shared__ int s[512];
  int v = (threadIdx.x < NB) ? bsum[threadIdx.x] : 0;
  s[threadIdx.x] = v;
  __syncthreads();
#pragma unroll
  for (int off = 1; off < 512; off <<= 1) {
    int t = (threadIdx.x >= off) ? s[threadIdx.x - off] : 0;
    __syncthreads();
    s[threadIdx.x] += t;
    __syncthreads();
  }
  if (threadIdx.x < NB) bsum[threadIdx.x] = s[threadIdx.x] - v;
}

__global__ __launch_bounds__(256) void fill(
    const int* __restrict__ row, const int* __restrict__ col,
    const int* __restrict__ rank, const int* __restrict__ base,
    const int* __restrict__ bsum, int* __restrict__ sorted_col, int E) {
  int e = blockIdx.x * 256 + threadIdx.x;
  if (e < E) {
    int r = row[e];
    sorted_col[base[r] + bsum[r >> 8] + rank[e]] = col[e];
  }
}

__global__ __launch_bounds__(256) void gather(
    const int* __restrict__ base, const int* __restrict__ bsum,
    const int* __restrict__ deg, const int* __restrict__ sorted_col,
    const float* __restrict__ el, const float* __restrict__ er,
    const ushort* __restrict__ Zh, float* __restrict__ out, int N) {
  int t = threadIdx.x;
  int lane = t & 63;
  int n = blockIdx.x * 4 + (t >> 6);
  if (n >= N) return;
  int h = lane & 3;                   // head
  int jj = lane >> 2;                 // edge sub-index within 16-chunk
  int s = base[n] + bsum[n >> 8];
  int d = deg[n];
  int end = s + d;
  float elv = el[((unsigned)n << 2) + h];
  float acc0 = 0.f, acc1 = 0.f, sumA = 0.f;
  const unsigned* Zh32 = (const unsigned*)Zh;
  const unsigned zlane = (unsigned)lane;
  const int bpb = (lane & 3) << 2;    // bpermute byte base: source = jj*4+h

  for (int p = s; p < end; p += 16) {
    int cnt = end - p;                // slots with jj < cnt are valid
    // phase A: one exp per (edge, head); quad-contiguous er loads
    int cl6 = 0;
    float xv = 0.f;
    if (jj < cnt) {
      int cl = sorted_col[p + jj];
      float e = elv + er[((unsigned)cl << 2) + h];
      e = fmaxf(e, 0.2f * e);          // LeakyReLU(0.2)
      xv = __expf(e);
      cl6 = cl << 6;                   // dword offset of Zh row
    }
    sumA += xv;
    // phase B: batched broadcasts, batched loads, batched fma (branch-free)
    float xvb[16];
    unsigned addr[16];
#pragma unroll
    for (int q = 0; q < 16; ++q) {
      int a = bpb + (q << 4);          // lane q*4+h
      xvb[q] = __builtin_bit_cast(float,
          __builtin_amdgcn_ds_bpermute(a, __builtin_bit_cast(int, xv)));
      addr[q] = (unsigned)__builtin_amdgcn_ds_bpermute(a, cl6) + zlane;
    }
    unsigned zz[16];
#pragma unroll
    for (int q = 0; q < 16; ++q) zz[q] = Zh32[addr[q]];
#pragma unroll
    for (int q = 0; q < 16; ++q) {
      acc0 = fmaf(xvb[q], __builtin_bit_cast(float, zz[q] << 16), acc0);
      acc1 = fmaf(xvb[q], __builtin_bit_cast(float, zz[q] & 0xffff0000u), acc1);
    }
  }
  // reduce denom over the 16 lanes of this head (bits 2..5)
  float sum = sumA;
  sum += __shfl_xor(sum, 4, 64);
  sum += __shfl_xor(sum, 8, 64);
  sum += __shfl_xor(sum, 16, 64);
  sum += __shfl_xor(sum, 32, 64);
  float inv = (d > 0) ? 1.0f / sum : 0.f;
  // lane = o'*4+h exactly -> coalesced stores
  unsigned ob = ((unsigned)n << 7) + zlane;
  __builtin_nontemporal_store(acc0 * inv, &out[ob]);
  __builtin_nontemporal_store(acc1 * inv, &out[ob + 64]);
}

extern "C" void kernel_launch(void* const* d_in, const int* in_sizes, int n_in,
                              void* d_out, int out_size, void* d_ws, size_t ws_size,
                              hipStream_t stream) {
  const float* x   = (const float*)d_in[0];
  const int*   row = (const int*)d_in[1];
  const int*   col = (const int*)d_in[2];
  const float* W   = (const float*)d_in[3];
  const float* b   = (const float*)d_in[4];
  const float* a_l = (const float*)d_in[5];
  const float* a_r = (const float*)d_in[6];
  float* out = (float*)d_out;

  const int N = in_sizes[0] / 128;
  const int E = in_sizes[1];
  const int NB = (N + 255) / 256;

  char* w = (char*)d_ws;
  ushort* Zh       = (ushort*)w;             w += (size_t)N * 128 * 2;
  int*   sorted_col= (int*)w;                w += (size_t)E * 4;
  int*   rank      = (int*)w;                w += (size_t)E * 4;
  float* el        = (float*)w;              w += (size_t)N * 4 * 4;
  float* er        = (float*)w;              w += (size_t)N * 4 * 4;
  int*   deg       = (int*)w;                w += (size_t)N * 4;
  int*   base      = (int*)w;                w += (size_t)N * 4;
  int*   bsum      = (int*)w;                w += 512 * 4;
  ushort* Wh       = (ushort*)w;             w += 16384 * 2;
  ushort* Wl       = (ushort*)w;             w += 16384 * 2;

  const int P0 = (N > 16384 ? N : 16384);
  prep0<<<(P0 + 511) / 512, 512, 0, stream>>>(W, Wh, Wl, deg, N);

  const int G1 = (N + 127) / 128;            // gemm blocks
  const int G2 = (E + 511) / 512;            // deg tail blocks
  gemm_deg<<<G1 + G2, 512, 0, stream>>>(x, Wh, Wl, b, a_l, a_r, Zh, el, er,
                                        N, row, deg, rank, E, G1);

  scan1<<<NB, 256, 0, stream>>>(deg, base, bsum, N);
  scan2<<<1, 512, 0, stream>>>(bsum, NB);
  fill<<<(E + 255) / 256, 256, 0, stream>>>(row, col, rank, base, bsum,
                                            sorted_col, E);
  gather<<<(N + 3) / 4, 256, 0, stream>>>(base, bsum, deg, sorted_col, el, er,
                                          Zh, out, N);
}